// Round 1
// baseline (164.499 us; speedup 1.0000x reference)
//
#include <hip/hip_runtime.h>
#include <math.h>

// Problem constants
#define BINS   256
#define NPAIR  24        // B*C = 8*3
#define NPIX   16384     // 128*128
#define SPLIT  16        // blocks per (tensor,channel)
#define PIXPB  (NPIX / SPLIT)   // 1024 pixels per block
#define WIN    16        // +/- bins in Gaussian window (>=6 sigma)

#define SIGMA    0.01f
#define DELTA    (1.0f / 255.0f)
#define INVS2    10000.0f                  // 1/sigma^2
#define INV_NORM 39.894228040143274f       // 1/(sigma*sqrt(2*pi))

__device__ __forceinline__ void global_fadd(float* p, float v) {
#if defined(__HIP_PLATFORM_AMD__)
  unsafeAtomicAdd(p, v);   // global_atomic_add_f32
#else
  atomicAdd(p, v);
#endif
}

// ---------------------------------------------------------------------------
// Kernel 1: soft histogram.
// grid = 48 * SPLIT blocks, 256 threads.
// blockIdx -> (pairglob in [0,48), split). pairglob < 24: target, else pred.
// Each thread: 4 pixels via float4. Per pixel: 3 expf + 2-mul/bin recurrence
// over +/-WIN bins, accumulated into per-wave LDS histogram replicas.
// ---------------------------------------------------------------------------
__global__ __launch_bounds__(256) void hist_kernel(
    const float* __restrict__ targ, const float* __restrict__ pred,
    float* __restrict__ g_hist) {
  __shared__ float h[4][BINS];   // one replica per wave

  const int t = threadIdx.x;
  const int rep = t >> 6;
  const int pairglob = blockIdx.x >> 4;       // 0..47
  const int split = blockIdx.x & (SPLIT - 1); // 0..15
  const int chan = (pairglob < NPAIR) ? pairglob : (pairglob - NPAIR);
  const float* __restrict__ src = (pairglob < NPAIR) ? targ : pred;

  // zero LDS replicas
  #pragma unroll
  for (int i = 0; i < 4; ++i) h[i][t & (BINS - 1)] = 0.0f;  // t<256 so this is h[i][t]
  __syncthreads();

  const float D2 = DELTA * DELTA;
  const float RHO = expf(-D2 * INVS2);        // constant step ratio

  const int base = chan * NPIX + split * PIXPB;
  const float4 px = reinterpret_cast<const float4*>(src + base)[t];
  const float xs[4] = {px.x, px.y, px.z, px.w};

  #pragma unroll
  for (int pi = 0; pi < 4; ++pi) {
    float x = xs[pi];
    int j0 = (int)(x * 255.0f + 0.5f);
    j0 = (j0 < 0) ? 0 : ((j0 > 255) ? 255 : j0);
    const float d = x - (float)j0 * DELTA;    // |d| <= DELTA/2

    const float u0 = expf(-0.5f * d * d * INVS2);
    atomicAdd(&h[rep][j0], u0);

    // upward: bins j0+1 .. j0+WIN
    {
      float u = u0;
      float q = expf((d * DELTA - 0.5f * D2) * INVS2);
      #pragma unroll
      for (int k = 1; k <= WIN; ++k) {
        u *= q;
        if (j0 + k < BINS) atomicAdd(&h[rep][j0 + k], u);
        q *= RHO;
      }
    }
    // downward: bins j0-1 .. j0-WIN
    {
      float u = u0;
      float q = expf((-d * DELTA - 0.5f * D2) * INVS2);
      #pragma unroll
      for (int k = 1; k <= WIN; ++k) {
        u *= q;
        if (j0 - k >= 0) atomicAdd(&h[rep][j0 - k], u);
        q *= RHO;
      }
    }
  }
  __syncthreads();

  // reduce replicas, one global atomic per bin
  const float s = h[0][t] + h[1][t] + h[2][t] + h[3][t];
  global_fadd(&g_hist[pairglob * BINS + t], s);
}

// ---------------------------------------------------------------------------
// Kernel 2: normalize + KL + mean. One block, 256 threads (thread t = bin t).
// ---------------------------------------------------------------------------
__device__ __forceinline__ float wave_sum(float v) {
  #pragma unroll
  for (int off = 32; off > 0; off >>= 1) v += __shfl_down(v, off, 64);
  return v;
}

__device__ __forceinline__ float block_sum_256(float v, float* red) {
  const int lane = threadIdx.x & 63, wv = threadIdx.x >> 6;
  v = wave_sum(v);
  __syncthreads();                 // protect red reuse across calls
  if (lane == 0) red[wv] = v;
  __syncthreads();
  return red[0] + red[1] + red[2] + red[3];
}

__global__ __launch_bounds__(256) void kl_kernel(
    const float* __restrict__ g_hist, float* __restrict__ out) {
  __shared__ float red[4];
  const int t = threadIdx.x;
  float acc = 0.0f;

  for (int p = 0; p < NPAIR; ++p) {
    const float ht = g_hist[p * BINS + t] * INV_NORM;
    const float hq = g_hist[(NPAIR + p) * BINS + t] * INV_NORM;
    const float st = block_sum_256(ht, red);
    const float sq = block_sum_256(hq, red);
    const float P = ht / (st + 1e-10f) + 1e-10f;
    const float Q = hq / (sq + 1e-10f) + 1e-10f;
    const float term = P * logf(P / Q);
    const float kl = block_sum_256(term, red);
    if (t == 0) acc += kl;
  }
  if (t == 0) out[0] = acc * (1.0f / NPAIR);
}

// ---------------------------------------------------------------------------
extern "C" void kernel_launch(void* const* d_in, const int* in_sizes, int n_in,
                              void* d_out, int out_size, void* d_ws, size_t ws_size,
                              hipStream_t stream) {
  const float* targ = (const float*)d_in[0];
  const float* pred = (const float*)d_in[1];
  float* g_hist = (float*)d_ws;          // 48 * 256 floats = 48 KiB
  float* out = (float*)d_out;

  hipMemsetAsync(g_hist, 0, 2 * NPAIR * BINS * sizeof(float), stream);
  hist_kernel<<<dim3(48 * SPLIT), dim3(256), 0, stream>>>(targ, pred, g_hist);
  kl_kernel<<<dim3(1), dim3(256), 0, stream>>>(g_hist, out);
}

// Round 3
// 148.102 us; speedup vs baseline: 1.1107x; 1.1107x over previous
//
#include <hip/hip_runtime.h>
#include <math.h>

// Problem constants
#define BINS   256
#define NPAIR  24        // B*C = 8*3
#define NPIX   16384     // 128*128
#define SPLIT  64        // blocks per (tensor,channel)
#define PIXPB  (NPIX / SPLIT)   // 256 pixels per block -> 1 per thread
#define WIN    16        // +/- bins in Gaussian window (>=6 sigma)
#define HPAD   288       // 16 + 256 + 16 padded histogram

#define DELTA    0.003921568859f           // 1/255
#define INVS2    10000.0f                  // 1/sigma^2
#define H2       0.07689350f               // 0.5*DELTA^2*INVS2
#define ADEL     39.21568627f              // DELTA*INVS2
#define RHO      0.85745472f               // exp(-2*H2)
#define INV_NORM 39.894228040143274f       // 1/(sigma*sqrt(2*pi))

__device__ __forceinline__ void global_fadd(float* p, float v) {
#if defined(__HIP_PLATFORM_AMD__)
  unsafeAtomicAdd(p, v);   // global_atomic_add_f32
#else
  atomicAdd(p, v);
#endif
}

// ---------------------------------------------------------------------------
// Kernel 1: soft histogram.
// grid = 48 * SPLIT blocks, 256 threads, 1 pixel/thread.
// Per pixel: 3 fast exps + branch-free 2-mul/bin recurrence over +/-16 bins
// into per-wave padded LDS replicas (pad absorbs out-of-range bins).
// ---------------------------------------------------------------------------
__global__ __launch_bounds__(256) void hist_kernel(
    const float* __restrict__ targ, const float* __restrict__ pred,
    float* __restrict__ g_hist) {
  __shared__ float h[4][HPAD];   // one replica per wave, padded +/-16

  const int t = threadIdx.x;
  const int rep = t >> 6;
  const int pg = blockIdx.x >> 6;        // 0..47
  const int split = blockIdx.x & (SPLIT - 1);
  const int chan = (pg < NPAIR) ? pg : (pg - NPAIR);
  const float* __restrict__ src = (pg < NPAIR) ? targ : pred;

  // zero LDS replicas (4*288 = 1152 words)
  #pragma unroll
  for (int i = t; i < 4 * HPAD; i += 256) ((float*)h)[i] = 0.0f;
  __syncthreads();

  const float x = src[chan * NPIX + split * PIXPB + t];
  const int j0 = (int)(x * 255.0f + 0.5f);     // x in [0,1) -> j0 in [0,255]
  const float d = x - (float)j0 * DELTA;       // |d| <= DELTA/2

  float* __restrict__ hr = &h[rep][16 + j0];

  const float u0 = __expf(-(0.5f * INVS2) * d * d);
  atomicAdd(&hr[0], u0);

  // upward bins j0+1..j0+16 (out-of-range lands in pad)
  {
    float u = u0;
    float q = __expf(ADEL * d - H2);
    #pragma unroll
    for (int k = 1; k <= WIN; ++k) {
      u *= q;
      atomicAdd(&hr[k], u);
      q *= RHO;
    }
  }
  // downward bins j0-1..j0-16
  {
    float u = u0;
    float q = __expf(-ADEL * d - H2);
    #pragma unroll
    for (int k = 1; k <= WIN; ++k) {
      u *= q;
      atomicAdd(&hr[-k], u);
      q *= RHO;
    }
  }
  __syncthreads();

  // reduce replicas (interior only), one global atomic per bin
  const float s = h[0][16 + t] + h[1][16 + t] + h[2][16 + t] + h[3][16 + t];
  global_fadd(&g_hist[pg * BINS + t], s);
}

// ---------------------------------------------------------------------------
// Kernel 2: normalize + KL + mean. One block, 4 waves; each wave owns 6
// (target,pred) pairs; butterfly shfl reductions, no per-pair barriers.
// ---------------------------------------------------------------------------
__device__ __forceinline__ float wave_allsum(float v) {
  #pragma unroll
  for (int off = 32; off > 0; off >>= 1) v += __shfl_xor(v, off, 64);
  return v;
}

__global__ __launch_bounds__(256) void kl_kernel(
    const float* __restrict__ g_hist, float* __restrict__ out) {
  __shared__ float red[4];
  const int t = threadIdx.x;
  const int lane = t & 63, wv = t >> 6;
  float acc = 0.0f;

  for (int i = 0; i < 6; ++i) {
    const int p = wv * 6 + i;
    float ht[4], hq[4];
    float st = 0.0f, sq = 0.0f;
    #pragma unroll
    for (int b = 0; b < 4; ++b) {
      ht[b] = g_hist[p * BINS + lane + 64 * b] * INV_NORM;
      hq[b] = g_hist[(NPAIR + p) * BINS + lane + 64 * b] * INV_NORM;
      st += ht[b];
      sq += hq[b];
    }
    st = wave_allsum(st);
    sq = wave_allsum(sq);
    float term = 0.0f;
    #pragma unroll
    for (int b = 0; b < 4; ++b) {
      const float P = ht[b] / (st + 1e-10f) + 1e-10f;
      const float Q = hq[b] / (sq + 1e-10f) + 1e-10f;
      term += P * __logf(P / Q);
    }
    term = wave_allsum(term);
    if (lane == 0) acc += term;
  }
  if (lane == 0) red[wv] = acc;
  __syncthreads();
  if (t == 0) out[0] = (red[0] + red[1] + red[2] + red[3]) * (1.0f / NPAIR);
}

// ---------------------------------------------------------------------------
extern "C" void kernel_launch(void* const* d_in, const int* in_sizes, int n_in,
                              void* d_out, int out_size, void* d_ws, size_t ws_size,
                              hipStream_t stream) {
  const float* targ = (const float*)d_in[0];
  const float* pred = (const float*)d_in[1];
  float* g_hist = (float*)d_ws;          // 48 * 256 floats = 48 KiB
  float* out = (float*)d_out;

  hipMemsetAsync(g_hist, 0, 2 * NPAIR * BINS * sizeof(float), stream);
  hist_kernel<<<dim3(48 * SPLIT), dim3(256), 0, stream>>>(targ, pred, g_hist);
  kl_kernel<<<dim3(1), dim3(256), 0, stream>>>(g_hist, out);
}

// Round 5
// 147.993 us; speedup vs baseline: 1.1115x; 1.0007x over previous
//
#include <hip/hip_runtime.h>
#include <math.h>

// Problem constants
#define BINS   256
#define NPAIR  24        // B*C = 8*3
#define NPIX   16384     // 128*128
#define SPLIT  64        // blocks per (tensor,channel)
#define PIXPB  (NPIX / SPLIT)   // 256 pixels per block -> 1 per thread
#define WIN    16        // +/- bins in Gaussian window (>=6 sigma)
#define HPAD   288       // 16 + 256 + 16 padded histogram

#define DELTA    0.003921568859f           // 1/255
#define INVS2    10000.0f                  // 1/sigma^2
#define H2       0.07689350f               // 0.5*DELTA^2*INVS2
#define ADEL     39.21568627f              // DELTA*INVS2
#define RHO      0.85745472f               // exp(-2*H2)
#define INV_NORM 39.894228040143274f       // 1/(sigma*sqrt(2*pi))

// Native f32 atomics. CRITICAL: plain atomicAdd(float*) on LDS emits an
// IEEE-safe CAS loop (~200 cyc/op — R3's wall). unsafeAtomicAdd lowers to
// ds_add_f32 (LDS) / global_atomic_add_f32 (global) on gfx950.
__device__ __forceinline__ void lds_fadd(float* p, float v) {
  unsafeAtomicAdd(p, v);
}
__device__ __forceinline__ void global_fadd(float* p, float v) {
  unsafeAtomicAdd(p, v);
}

// ---------------------------------------------------------------------------
// Kernel 1: soft histogram.
// grid = 48 * SPLIT blocks, 256 threads, 1 pixel/thread.
// Per pixel: 3 fast exps + branch-free 2-mul/bin recurrence over +/-16 bins
// into per-wave padded LDS replicas (pad absorbs out-of-range bins).
// ---------------------------------------------------------------------------
__global__ __launch_bounds__(256) void hist_kernel(
    const float* __restrict__ targ, const float* __restrict__ pred,
    float* __restrict__ g_hist) {
  __shared__ float h[4][HPAD];   // one replica per wave, padded +/-16

  const int t = threadIdx.x;
  const int rep = t >> 6;
  const int pg = blockIdx.x >> 6;        // 0..47
  const int split = blockIdx.x & (SPLIT - 1);
  const int chan = (pg < NPAIR) ? pg : (pg - NPAIR);
  const float* __restrict__ src = (pg < NPAIR) ? targ : pred;

  // zero LDS replicas (4*288 = 1152 words)
  #pragma unroll
  for (int i = t; i < 4 * HPAD; i += 256) ((float*)h)[i] = 0.0f;
  __syncthreads();

  const float x = src[chan * NPIX + split * PIXPB + t];
  const int j0 = (int)(x * 255.0f + 0.5f);     // x in [0,1) -> j0 in [0,255]
  const float d = x - (float)j0 * DELTA;       // |d| <= DELTA/2

  float* __restrict__ hr = &h[rep][16 + j0];

  const float u0 = __expf(-(0.5f * INVS2) * d * d);
  lds_fadd(&hr[0], u0);

  // upward bins j0+1..j0+16 (out-of-range lands in pad)
  {
    float u = u0;
    float q = __expf(ADEL * d - H2);
    #pragma unroll
    for (int k = 1; k <= WIN; ++k) {
      u *= q;
      lds_fadd(&hr[k], u);
      q *= RHO;
    }
  }
  // downward bins j0-1..j0-16
  {
    float u = u0;
    float q = __expf(-ADEL * d - H2);
    #pragma unroll
    for (int k = 1; k <= WIN; ++k) {
      u *= q;
      lds_fadd(&hr[-k], u);
      q *= RHO;
    }
  }
  __syncthreads();

  // reduce replicas (interior only), one global atomic per bin
  const float s = h[0][16 + t] + h[1][16 + t] + h[2][16 + t] + h[3][16 + t];
  global_fadd(&g_hist[pg * BINS + t], s);
}

// ---------------------------------------------------------------------------
// Kernel 2: normalize + KL + mean. One block, 4 waves; each wave owns 6
// (target,pred) pairs; butterfly shfl reductions, no per-pair barriers.
// ---------------------------------------------------------------------------
__device__ __forceinline__ float wave_allsum(float v) {
  #pragma unroll
  for (int off = 32; off > 0; off >>= 1) v += __shfl_xor(v, off, 64);
  return v;
}

__global__ __launch_bounds__(256) void kl_kernel(
    const float* __restrict__ g_hist, float* __restrict__ out) {
  __shared__ float red[4];
  const int t = threadIdx.x;
  const int lane = t & 63, wv = t >> 6;
  float acc = 0.0f;

  for (int i = 0; i < 6; ++i) {
    const int p = wv * 6 + i;
    float ht[4], hq[4];
    float st = 0.0f, sq = 0.0f;
    #pragma unroll
    for (int b = 0; b < 4; ++b) {
      ht[b] = g_hist[p * BINS + lane + 64 * b] * INV_NORM;
      hq[b] = g_hist[(NPAIR + p) * BINS + lane + 64 * b] * INV_NORM;
      st += ht[b];
      sq += hq[b];
    }
    st = wave_allsum(st);
    sq = wave_allsum(sq);
    float term = 0.0f;
    #pragma unroll
    for (int b = 0; b < 4; ++b) {
      const float P = ht[b] / (st + 1e-10f) + 1e-10f;
      const float Q = hq[b] / (sq + 1e-10f) + 1e-10f;
      term += P * __logf(P / Q);
    }
    term = wave_allsum(term);
    if (lane == 0) acc += term;
  }
  if (lane == 0) red[wv] = acc;
  __syncthreads();
  if (t == 0) out[0] = (red[0] + red[1] + red[2] + red[3]) * (1.0f / NPAIR);
}

// ---------------------------------------------------------------------------
extern "C" void kernel_launch(void* const* d_in, const int* in_sizes, int n_in,
                              void* d_out, int out_size, void* d_ws, size_t ws_size,
                              hipStream_t stream) {
  const float* targ = (const float*)d_in[0];
  const float* pred = (const float*)d_in[1];
  float* g_hist = (float*)d_ws;          // 48 * 256 floats = 48 KiB
  float* out = (float*)d_out;

  hipMemsetAsync(g_hist, 0, 2 * NPAIR * BINS * sizeof(float), stream);
  hist_kernel<<<dim3(48 * SPLIT), dim3(256), 0, stream>>>(targ, pred, g_hist);
  kl_kernel<<<dim3(1), dim3(256), 0, stream>>>(g_hist, out);
}

// Round 9
// 44.770 us; speedup vs baseline: 3.6743x; 3.3056x over previous
//
#include <hip/hip_runtime.h>
#include <math.h>

// Problem constants
#define BINS   256
#define NPAIR  24        // B*C = 8*3
#define NPIX   16384     // 128*128
#define SPLIT  16        // blocks per (tensor,channel): 768 blocks = 3/CU

#define DELTA    0.003921568859f           // 1/255 (bin pitch of linspace(0,1,256))
#define NK       -5000.0f                  // -1/(2*sigma^2)
#define A2K      39.21568627f              // 2*K*DELTA   (K=5000)
#define B2K      0.07689350f               // K*DELTA^2
#define RHO      0.85745472f               // exp(-2*K*DELTA^2)
#define INV_NORM 39.894228040143274f       // 1/(sigma*sqrt(2*pi))

__device__ __forceinline__ void global_fadd(float* p, float v) {
  unsafeAtomicAdd(p, v);   // global_atomic_add_f32
}
__device__ __forceinline__ float bcast(float v, int i) {
  // wave-uniform lane read (v_readlane_b32 with SGPR index)
  return __uint_as_float(__builtin_amdgcn_readlane(__float_as_uint(v), i));
}

// ---------------------------------------------------------------------------
// Kernel 1: soft histogram, register-resident (NO LDS atomics — R3/R5 showed
// the DS atomic unit serializes per-lane at ~3.1 cyc/lane-op = the 132 us wall).
// Lane l owns bins {4l..4l+3} in 4 VGPRs. Pixels broadcast via readlane; every
// lane computes its 4 dense Gaussian weights (2 exp + mul recurrence) and
// accumulates in registers. Epilogue: LDS combine across 4 waves, one global
// atomic per bin per block.
// ---------------------------------------------------------------------------
__global__ __launch_bounds__(256) void hist_kernel(
    const float* __restrict__ targ, const float* __restrict__ pred,
    float* __restrict__ g_hist) {
  __shared__ float h[4][BINS];

  const int t = threadIdx.x, lane = t & 63, wv = t >> 6;
  const int pg = blockIdx.x >> 4;            // 0..47
  const int split = blockIdx.x & (SPLIT - 1);
  const int chan = (pg < NPAIR) ? pg : pg - NPAIR;
  const float* __restrict__ src = (pg < NPAIR) ? targ : pred;

  const float c0 = (float)(4 * lane) * DELTA;   // center of lane's first bin
  float a0 = 0.f, a1 = 0.f, a2 = 0.f, a3 = 0.f;

  // wave wv covers 256 consecutive pixels: 64 lanes x float4
  const float4 px = reinterpret_cast<const float4*>(
      src + chan * NPIX + split * (NPIX / SPLIT) + wv * 256)[lane];

  auto accum = [&](float x) {
    const float d0 = x - c0;
    float w = __expf(NK * d0 * d0);        // weight of bin 4l
    float q = __expf(A2K * d0 - B2K);      // ratio w(4l+1)/w(4l)
    a0 += w;
    w *= q; q *= RHO; a1 += w;             // q_{j+1} = q_j * exp(-2K*DELTA^2)
    w *= q; q *= RHO; a2 += w;
    w *= q;           a3 += w;
  };

  #pragma unroll 4
  for (int i = 0; i < 64; ++i) {
    const float x0 = bcast(px.x, i), x1 = bcast(px.y, i);
    const float x2 = bcast(px.z, i), x3 = bcast(px.w, i);
    accum(x0); accum(x1); accum(x2); accum(x3);   // 4 indep chains = ILP
  }

  // combine the block's 4 waves in LDS (plain writes), then global atomic
  reinterpret_cast<float4*>(&h[wv][4 * lane])[0] = make_float4(a0, a1, a2, a3);
  __syncthreads();
  const float s = h[0][t] + h[1][t] + h[2][t] + h[3][t];
  global_fadd(&g_hist[pg * BINS + t], s);
}

// ---------------------------------------------------------------------------
// Kernel 2: normalize + KL + mean. One block, 4 waves; each wave owns 6
// (target,pred) pairs; butterfly shfl reductions, no per-pair barriers.
// (unchanged from R5 — proven correct, not the bottleneck)
// ---------------------------------------------------------------------------
__device__ __forceinline__ float wave_allsum(float v) {
  #pragma unroll
  for (int off = 32; off > 0; off >>= 1) v += __shfl_xor(v, off, 64);
  return v;
}

__global__ __launch_bounds__(256) void kl_kernel(
    const float* __restrict__ g_hist, float* __restrict__ out) {
  __shared__ float red[4];
  const int t = threadIdx.x;
  const int lane = t & 63, wv = t >> 6;
  float acc = 0.0f;

  for (int i = 0; i < 6; ++i) {
    const int p = wv * 6 + i;
    float ht[4], hq[4];
    float st = 0.0f, sq = 0.0f;
    #pragma unroll
    for (int b = 0; b < 4; ++b) {
      ht[b] = g_hist[p * BINS + lane + 64 * b] * INV_NORM;
      hq[b] = g_hist[(NPAIR + p) * BINS + lane + 64 * b] * INV_NORM;
      st += ht[b];
      sq += hq[b];
    }
    st = wave_allsum(st);
    sq = wave_allsum(sq);
    float term = 0.0f;
    #pragma unroll
    for (int b = 0; b < 4; ++b) {
      const float P = ht[b] / (st + 1e-10f) + 1e-10f;
      const float Q = hq[b] / (sq + 1e-10f) + 1e-10f;
      term += P * __logf(P / Q);
    }
    term = wave_allsum(term);
    if (lane == 0) acc += term;
  }
  if (lane == 0) red[wv] = acc;
  __syncthreads();
  if (t == 0) out[0] = (red[0] + red[1] + red[2] + red[3]) * (1.0f / NPAIR);
}

// ---------------------------------------------------------------------------
extern "C" void kernel_launch(void* const* d_in, const int* in_sizes, int n_in,
                              void* d_out, int out_size, void* d_ws, size_t ws_size,
                              hipStream_t stream) {
  const float* targ = (const float*)d_in[0];
  const float* pred = (const float*)d_in[1];
  float* g_hist = (float*)d_ws;          // 48 * 256 floats = 48 KiB
  float* out = (float*)d_out;

  hipMemsetAsync(g_hist, 0, 2 * NPAIR * BINS * sizeof(float), stream);
  hist_kernel<<<dim3(48 * SPLIT), dim3(256), 0, stream>>>(targ, pred, g_hist);
  kl_kernel<<<dim3(1), dim3(256), 0, stream>>>(g_hist, out);
}

// Round 10
// 33.745 us; speedup vs baseline: 4.8748x; 1.3267x over previous
//
#include <hip/hip_runtime.h>
#include <math.h>

// Problem constants
#define BINS   256
#define NPAIR  24        // B*C = 8*3
#define NPIX   16384     // 128*128
#define SPLIT  16        // blocks per (tensor,channel)
#define NBLK   (48 * SPLIT)   // 768 blocks = 3/CU

#define DELTA    0.003921568859f           // 1/255 (bin pitch)
#define NK       -5000.0f                  // -1/(2*sigma^2)
#define A2K      39.21568627f              // 10000*DELTA
#define B2K      0.07689350f               // 5000*DELTA^2
#define RHO      0.85745472f               // exp(-2*5000*DELTA^2)
#define INV_NORM 39.894228040143274f       // 1/(sigma*sqrt(2*pi))

__device__ __forceinline__ float bcast(float v, int i) {
  return __uint_as_float(__builtin_amdgcn_readlane(__float_as_uint(v), i));
}

// ---------------------------------------------------------------------------
// Kernel 1: soft histogram, register-gather, 16 bins/lane.
// Lane layout: lsub = lane&15 owns bins 16*lsub..16*lsub+15; subgroup
// g = lane>>4 processes pixel 4r+g of round r (component g of lane r's
// float4, selected by 2 cndmasks). The 2 exps + 15-step mul recurrence
// serve 16 bins -> ~33 cyc/px vs R9's ~65 (exps amortized 4x).
// Epilogue: plain LDS combine + plain global store of per-block partials
// (no atomics => no memset dispatch needed).
// ---------------------------------------------------------------------------
__global__ __launch_bounds__(256) void hist_kernel(
    const float* __restrict__ targ, const float* __restrict__ pred,
    float* __restrict__ g_part) {
  __shared__ float h[4][4][BINS];   // [wave][subgroup][bin] = 16 KiB

  const int t = threadIdx.x, lane = t & 63, wv = t >> 6;
  const int g = lane >> 4, lsub = lane & 15;
  const int pg = blockIdx.x >> 4;            // 0..47
  const int split = blockIdx.x & (SPLIT - 1);
  const int chan = (pg < NPAIR) ? pg : pg - NPAIR;
  const float* __restrict__ src = (pg < NPAIR) ? targ : pred;

  const float c0 = (float)(16 * lsub) * DELTA;  // lane's first bin center
  const bool b0 = (g & 1) != 0;
  const bool b1 = (g >> 1) != 0;

  float a[16];
  #pragma unroll
  for (int i = 0; i < 16; ++i) a[i] = 0.f;

  // wave covers 256 consecutive pixels: 64 lanes x float4
  const float4 px = reinterpret_cast<const float4*>(
      src + chan * NPIX + split * 1024 + wv * 256)[lane];

  #pragma unroll 4
  for (int r = 0; r < 64; ++r) {
    const float s0 = bcast(px.x, r), s1 = bcast(px.y, r);
    const float s2 = bcast(px.z, r), s3 = bcast(px.w, r);
    const float lo = b0 ? s1 : s0;
    const float hi = b0 ? s3 : s2;
    const float x  = b1 ? hi : lo;            // pixel 4r+g

    const float d = x - c0;
    float w = __expf(NK * d * d);             // weight of bin 16*lsub
    float q = __expf(A2K * d - B2K);          // ratio to next bin
    a[0] += w;
    #pragma unroll
    for (int i = 1; i < 16; ++i) { w *= q; q *= RHO; a[i] += w; }
  }

  // block combine: 16 (wave,subgroup) partials -> one 256-bin block partial
  #pragma unroll
  for (int i = 0; i < 16; i += 4)
    reinterpret_cast<float4*>(&h[wv][g][16 * lsub + i])[0] =
        make_float4(a[i], a[i + 1], a[i + 2], a[i + 3]);
  __syncthreads();

  float s = 0.f;
  #pragma unroll
  for (int w2 = 0; w2 < 4; ++w2)
    #pragma unroll
    for (int g2 = 0; g2 < 4; ++g2) s += h[w2][g2][t];
  g_part[blockIdx.x * BINS + t] = s;          // blockIdx = pg*SPLIT+split
}

// ---------------------------------------------------------------------------
// Reductions
// ---------------------------------------------------------------------------
__device__ __forceinline__ float wave_allsum(float v) {
  #pragma unroll
  for (int off = 32; off > 0; off >>= 1) v += __shfl_xor(v, off, 64);
  return v;
}
__device__ __forceinline__ float block_sum(float v, float* red, int lane, int wv) {
  v = wave_allsum(v);
  __syncthreads();
  if (lane == 0) red[wv] = v;
  __syncthreads();
  return red[0] + red[1] + red[2] + red[3];
}

// ---------------------------------------------------------------------------
// Kernel 2: per-pair KL. 24 blocks; block p reduces its 2x16 partials,
// normalizes, computes sum_bins P*log(P/Q), writes g_klp[p].
// ---------------------------------------------------------------------------
__global__ __launch_bounds__(256) void klpair_kernel(
    const float* __restrict__ g_part, float* __restrict__ g_klp) {
  __shared__ float red[4];
  const int t = threadIdx.x, lane = t & 63, wv = t >> 6;
  const int p = blockIdx.x;

  float ht = 0.f, hq = 0.f;
  #pragma unroll
  for (int s = 0; s < SPLIT; ++s) {
    ht += g_part[(p * SPLIT + s) * BINS + t];
    hq += g_part[((NPAIR + p) * SPLIT + s) * BINS + t];
  }
  ht *= INV_NORM;
  hq *= INV_NORM;

  const float st = block_sum(ht, red, lane, wv);
  const float sq = block_sum(hq, red, lane, wv);
  const float P = ht / (st + 1e-10f) + 1e-10f;
  const float Q = hq / (sq + 1e-10f) + 1e-10f;
  const float kl = block_sum(P * __logf(P / Q), red, lane, wv);
  if (t == 0) g_klp[p] = kl;
}

// ---------------------------------------------------------------------------
// Kernel 3: mean of 24 KLs -> scalar.
// ---------------------------------------------------------------------------
__global__ __launch_bounds__(64) void final_kernel(
    const float* __restrict__ g_klp, float* __restrict__ out) {
  const int lane = threadIdx.x;
  float v = (lane < NPAIR) ? g_klp[lane] : 0.f;
  v = wave_allsum(v);
  if (lane == 0) out[0] = v * (1.0f / NPAIR);
}

// ---------------------------------------------------------------------------
extern "C" void kernel_launch(void* const* d_in, const int* in_sizes, int n_in,
                              void* d_out, int out_size, void* d_ws, size_t ws_size,
                              hipStream_t stream) {
  const float* targ = (const float*)d_in[0];
  const float* pred = (const float*)d_in[1];
  float* g_part = (float*)d_ws;             // 768*256 f32 = 768 KiB
  float* g_klp  = g_part + NBLK * BINS;     // 24 f32
  float* out = (float*)d_out;

  hist_kernel<<<dim3(NBLK), dim3(256), 0, stream>>>(targ, pred, g_part);
  klpair_kernel<<<dim3(NPAIR), dim3(256), 0, stream>>>(g_part, g_klp);
  final_kernel<<<dim3(1), dim3(64), 0, stream>>>(g_klp, out);
}